// Round 6
// baseline (710.031 us; speedup 1.0000x reference)
//
#include <hip/hip_runtime.h>
#include <math.h>

// Problem constants
constexpr int Bc = 8, Tc = 256, Dc = 512, Mc = 128, Lc = 4, Vc = 32000;
constexpr int Rc = Bc * Tc;          // 2048 rows
constexpr int Hc = 4 * Dc;           // 2048 hidden

typedef __bf16 bf16_t;
typedef __bf16 bf16x8 __attribute__((ext_vector_type(8)));
typedef float f32x4 __attribute__((ext_vector_type(4)));
static_assert(sizeof(bf16x8) == 16, "bf16x8 must be 16B");

#define DEV __device__ __forceinline__

DEV float wred64(float x) {
#pragma unroll
  for (int o = 32; o; o >>= 1) x += __shfl_xor(x, o);
  return x;
}

// ---------------------------------------------------------------- merged fp32 -> bf16 convert
// segments (in 2048-elem blocks): center 8000 | w1 2048 | w2 2048 | wo 128  => 12224 blocks
__global__ __launch_bounds__(256) void cvtall_k(const float* __restrict__ s0, bf16_t* __restrict__ d0,
                                                const float* __restrict__ s1, bf16_t* __restrict__ d1,
                                                const float* __restrict__ s2, bf16_t* __restrict__ d2,
                                                const float* __restrict__ s3, bf16_t* __restrict__ d3) {
  int blk = blockIdx.x;
  const float* src; bf16_t* dst; int base;
  if (blk < 8000)       { src = s0; dst = d0; base = blk; }
  else if (blk < 10048) { src = s1; dst = d1; base = blk - 8000; }
  else if (blk < 12096) { src = s2; dst = d2; base = blk - 10048; }
  else                  { src = s3; dst = d3; base = blk - 12096; }
  size_t i = (size_t)base * 2048 + (size_t)threadIdx.x * 8;
  float4 a = *(const float4*)(src + i);
  float4 b = *(const float4*)(src + i + 4);
  bf16_t o[8] = {(bf16_t)a.x, (bf16_t)a.y, (bf16_t)a.z, (bf16_t)a.w,
                 (bf16_t)b.x, (bf16_t)b.y, (bf16_t)b.z, (bf16_t)b.w};
  *(bf16x8*)(dst + i) = *(bf16x8*)o;
}

// pack wk|wq|wv|wgw|wgf|zeros -> [L][512][512] bf16
__global__ __launch_bounds__(128) void packkqv_k(const float* __restrict__ wk,
                                                 const float* __restrict__ wq,
                                                 const float* __restrict__ wv,
                                                 const float* __restrict__ wgw,
                                                 const float* __restrict__ wgf,
                                                 bf16_t* __restrict__ out) {
  int row = blockIdx.x;               // 0 .. L*512-1
  int lyr = row >> 9, o = row & 511;
  const float* src = nullptr;
  if (o < 128) src = wk + ((size_t)lyr * 128 + o) * Dc;
  else if (o < 256) src = wq + ((size_t)lyr * 128 + (o - 128)) * Dc;
  else if (o < 384) src = wv + ((size_t)lyr * 128 + (o - 256)) * Dc;
  else if (o == 384) src = wgw + (size_t)lyr * Dc;
  else if (o == 385) src = wgf + (size_t)lyr * Dc;
  int t = threadIdx.x;
  bf16_t* dst = out + (size_t)row * Dc + t * 4;
  if (src) {
    float4 v = ((const float4*)src)[t];
    dst[0] = (bf16_t)v.x; dst[1] = (bf16_t)v.y; dst[2] = (bf16_t)v.z; dst[3] = (bf16_t)v.w;
  } else {
    dst[0] = dst[1] = dst[2] = dst[3] = (bf16_t)0.f;
  }
}

__global__ __launch_bounds__(256) void packb_k(const float* __restrict__ bk,
                                               const float* __restrict__ bq,
                                               const float* __restrict__ bv,
                                               const float* __restrict__ bgw,
                                               const float* __restrict__ bgf,
                                               float* __restrict__ out) {
  int i = blockIdx.x * 256 + threadIdx.x;
  if (i >= Lc * 512) return;
  int lyr = i >> 9, o = i & 511;
  float v = 0.f;
  if (o < 128) v = bk[lyr * 128 + o];
  else if (o < 256) v = bq[lyr * 128 + o - 128];
  else if (o < 384) v = bv[lyr * 128 + o - 256];
  else if (o == 384) v = bgw[lyr];
  else if (o == 385) v = bgf[lyr];
  out[i] = v;
}

// ---------------------------------------------------------------- gather + first LN (fused)
__global__ __launch_bounds__(64) void gl_k(const int* __restrict__ idx,
                                           const float* __restrict__ center,
                                           const float* __restrict__ g,
                                           const float* __restrict__ b,
                                           float* __restrict__ x,
                                           bf16_t* __restrict__ xn) {
  int r = blockIdx.x, t = threadIdx.x;
  const float4* row = (const float4*)(center + (size_t)idx[r] * Dc);
  float xv[8];
  *(float4*)&xv[0] = row[2 * t];
  *(float4*)&xv[4] = row[2 * t + 1];
  float4* xrow = (float4*)(x + (size_t)r * Dc);
  xrow[2 * t] = *(float4*)&xv[0];
  xrow[2 * t + 1] = *(float4*)&xv[4];
  float s = 0.f, ss = 0.f;
#pragma unroll
  for (int e = 0; e < 8; ++e) { s += xv[e]; ss += xv[e] * xv[e]; }
  s = wred64(s); ss = wred64(ss);
  float mu = s * (1.f / Dc);
  float inv = 1.f / sqrtf(ss * (1.f / Dc) - mu * mu + 1e-5f);
  float gg[8], bb[8];
  *(float4*)&gg[0] = ((const float4*)g)[2 * t];
  *(float4*)&gg[4] = ((const float4*)g)[2 * t + 1];
  *(float4*)&bb[0] = ((const float4*)b)[2 * t];
  *(float4*)&bb[4] = ((const float4*)b)[2 * t + 1];
  bf16_t ob[8];
#pragma unroll
  for (int e = 0; e < 8; ++e) ob[e] = (bf16_t)((xv[e] - mu) * inv * gg[e] + bb[e]);
  *(bf16x8*)(xn + (size_t)r * Dc + t * 8) = *(bf16x8*)ob;
}

// ---------------------------------------------------------------- LayerNorm -> bf16 (ln2)
__global__ __launch_bounds__(64) void ln_k(const float* __restrict__ in,
                                           const float* __restrict__ g,
                                           const float* __restrict__ b,
                                           bf16_t* __restrict__ out) {
  int r = blockIdx.x, t = threadIdx.x;
  const float4* row = (const float4*)(in + (size_t)r * Dc);
  float xv[8];
  *(float4*)&xv[0] = row[2 * t];
  *(float4*)&xv[4] = row[2 * t + 1];
  float s = 0.f, ss = 0.f;
#pragma unroll
  for (int e = 0; e < 8; ++e) { s += xv[e]; ss += xv[e] * xv[e]; }
  s = wred64(s); ss = wred64(ss);
  float mu = s * (1.f / Dc);
  float inv = 1.f / sqrtf(ss * (1.f / Dc) - mu * mu + 1e-5f);
  float gg[8], bb[8];
  *(float4*)&gg[0] = ((const float4*)g)[2 * t];
  *(float4*)&gg[4] = ((const float4*)g)[2 * t + 1];
  *(float4*)&bb[0] = ((const float4*)b)[2 * t];
  *(float4*)&bb[4] = ((const float4*)b)[2 * t + 1];
  bf16_t ob[8];
#pragma unroll
  for (int e = 0; e < 8; ++e) ob[e] = (bf16_t)((xv[e] - mu) * inv * gg[e] + bb[e]);
  *(bf16x8*)(out + (size_t)r * Dc + t * 8) = *(bf16x8*)ob;
}

// ---------------------------------------------------------------- split-K reduce + bias + residual + LN
__global__ __launch_bounds__(64) void redln_k(const float* __restrict__ part,
                                              const float* __restrict__ bias,
                                              float* __restrict__ x,
                                              const float* __restrict__ g,
                                              const float* __restrict__ b,
                                              bf16_t* __restrict__ xn) {
  int r = blockIdx.x, t = threadIdx.x;
  const float4* xr = (const float4*)(x + (size_t)r * Dc);
  const float4* p0 = (const float4*)(part + (size_t)r * Dc);
  const float4* p1 = (const float4*)(part + (size_t)(Rc + r) * Dc);
  const float4* bb4 = (const float4*)bias;
  float xv[8];
#pragma unroll
  for (int j = 0; j < 2; ++j) {
    float4 a = xr[2 * t + j], q = p0[2 * t + j], w = p1[2 * t + j], c = bb4[2 * t + j];
    xv[4 * j + 0] = a.x + q.x + w.x + c.x;
    xv[4 * j + 1] = a.y + q.y + w.y + c.y;
    xv[4 * j + 2] = a.z + q.z + w.z + c.z;
    xv[4 * j + 3] = a.w + q.w + w.w + c.w;
  }
  float4* xw = (float4*)(x + (size_t)r * Dc);
  xw[2 * t] = *(float4*)&xv[0];
  xw[2 * t + 1] = *(float4*)&xv[4];
  float s = 0.f, ss = 0.f;
#pragma unroll
  for (int e = 0; e < 8; ++e) { s += xv[e]; ss += xv[e] * xv[e]; }
  s = wred64(s); ss = wred64(ss);
  float mu = s * (1.f / Dc);
  float inv = 1.f / sqrtf(ss * (1.f / Dc) - mu * mu + 1e-5f);
  float gg[8], bv[8];
  *(float4*)&gg[0] = ((const float4*)g)[2 * t];
  *(float4*)&gg[4] = ((const float4*)g)[2 * t + 1];
  *(float4*)&bv[0] = ((const float4*)b)[2 * t];
  *(float4*)&bv[4] = ((const float4*)b)[2 * t + 1];
  bf16_t ob[8];
#pragma unroll
  for (int e = 0; e < 8; ++e) ob[e] = (bf16_t)((xv[e] - mu) * inv * gg[e] + bv[e]);
  *(bf16x8*)(xn + (size_t)r * Dc + t * 8) = *(bf16x8*)ob;
}

// ---------------------------------------------------------------- fused scan + l2norm + transposes (64 blocks)
// each block redundantly scans its batch's 256 log-gf (cheap); block x==0 writes cb.
__global__ __launch_bounds__(256) void prep_k(const float* __restrict__ kqv,
                                              const float* __restrict__ gwb,
                                              const float* __restrict__ gfb,
                                              float* __restrict__ cb,
                                              bf16_t* __restrict__ kb, bf16_t* __restrict__ qb,
                                              bf16_t* __restrict__ kt, bf16_t* __restrict__ vt,
                                              bf16_t* __restrict__ vtw) {
  __shared__ float tile[32][385];   // +1 pad -> conflict-free column reads
  __shared__ float sc[Tc];
  __shared__ float rnk[32], rnq[32], sw[32];
  int b = blockIdx.y, s0 = blockIdx.x * 32, t = threadIdx.x;
  // decay prefix scan over the whole batch (redundant per block)
  sc[t] = logf(gfb[b * Tc + t]);
  __syncthreads();
  for (int o = 1; o < Tc; o <<= 1) {
    float v = (t >= o) ? sc[t - o] : 0.f;
    __syncthreads();
    sc[t] += v;
    __syncthreads();
  }
  if (blockIdx.x == 0) cb[b * Tc + t] = sc[t];
  if (t < 32) sw[t] = gwb[b * Tc + s0 + t] * expf(sc[Tc - 1] - sc[s0 + t]);

  const float* src = kqv + (size_t)(b * Tc + s0) * 384;
#pragma unroll
  for (int i = 0; i < 12; ++i) {
    int c = t + i * 256;
    int row = c / 96, c4 = (c % 96) * 4;
    float4 v = *(const float4*)(src + (size_t)row * 384 + c4);
    tile[row][c4] = v.x; tile[row][c4 + 1] = v.y; tile[row][c4 + 2] = v.z; tile[row][c4 + 3] = v.w;
  }
  __syncthreads();
  {
    int row = t >> 3, sub = t & 7;
    float sk = 0.f, sq = 0.f;
#pragma unroll
    for (int e = 0; e < 16; ++e) {
      float a = tile[row][sub * 16 + e]; sk += a * a;
      float c = tile[row][128 + sub * 16 + e]; sq += c * c;
    }
#pragma unroll
    for (int o = 1; o < 8; o <<= 1) { sk += __shfl_xor(sk, o); sq += __shfl_xor(sq, o); }
    if (!sub) { rnk[row] = 1.f / fmaxf(sqrtf(sk), 1e-12f); rnq[row] = 1.f / fmaxf(sqrtf(sq), 1e-12f); }
  }
  __syncthreads();
  // row-major normalized k,q
#pragma unroll
  for (int i = 0; i < 2; ++i) {
    int c = t + i * 256;
    int row = c >> 4, e8 = (c & 15) * 8;
    float rk = rnk[row], rq = rnq[row];
    bf16_t ok[8], oq[8];
#pragma unroll
    for (int e = 0; e < 8; ++e) {
      ok[e] = (bf16_t)(tile[row][e8 + e] * rk);
      oq[e] = (bf16_t)(tile[row][128 + e8 + e] * rq);
    }
    size_t ro = (size_t)(b * Tc + s0 + row) * Mc + e8;
    *(bf16x8*)(kb + ro) = *(bf16x8*)ok;
    *(bf16x8*)(qb + ro) = *(bf16x8*)oq;
  }
  // transposed kt / vt / vtw
#pragma unroll
  for (int i = 0; i < 2; ++i) {
    int c = t + i * 256;
    int d = c >> 2, s8 = (c & 3) * 8;
    bf16_t a0[8], a1[8], a2[8];
#pragma unroll
    for (int e = 0; e < 8; ++e) {
      int s = s8 + e;
      a0[e] = (bf16_t)(tile[s][d] * rnk[s]);
      float v = tile[s][256 + d];
      a1[e] = (bf16_t)v;
      a2[e] = (bf16_t)(v * sw[s]);
    }
    size_t oo = ((size_t)b * Mc + d) * Tc + s0 + s8;
    *(bf16x8*)(kt + oo) = *(bf16x8*)a0;
    *(bf16x8*)(vt + oo) = *(bf16x8*)a1;
    *(bf16x8*)(vtw + oo) = *(bf16x8*)a2;
  }
}

// ---------------------------------------------------------------- MFMA helpers
DEV int swz_eoff(int row, int kbyte) {
  return row * 64 + ((kbyte ^ ((row & 7) << 4)) >> 1);
}

enum { A_NONE = 0, A_KQV = 1, A_GELU = 2 };

// shared epilogue
template <int ACT, bool ACCUM, bool SCALE, bool OBF16>
DEV void mm_epi(f32x4 (&acc)[4][4], int bm, int bn, int wm, int wn, int lhi, int l15,
                void* Cv, const float* bias, int ldc, long long sC, int z,
                float sc, float* o0, float* o1) {
  float* Cf = (float*)Cv;
  bf16_t* Cb = (bf16_t*)Cv;
#pragma unroll
  for (int m = 0; m < 4; ++m) {
#pragma unroll
    for (int n = 0; n < 4; ++n) {
#pragma unroll
      for (int q = 0; q < 4; ++q) {
        int row = bm + wm + m * 16 + lhi * 4 + q;   // C/D: col=lane&15, row=(lane>>4)*4+reg (m89)
        int col = bn + wn + n * 16 + l15;
        float val = acc[m][n][q];
        if (bias) val += bias[col];
        if (ACT == A_KQV) {
          if (col < 256) {
            Cf[(size_t)row * ldc + col] = val;
          } else if (col < 384) {
            Cf[(size_t)row * ldc + col] = tanhf(val);
          } else if (col == 384) {
            o0[row] = 1.f / (1.f + expf(-val));
          } else if (col == 385) {
            o1[row] = 0.9f / (1.f + expf(-val));
          }
          continue;
        }
        if (ACT == A_GELU) {
          val = 0.5f * val * (1.f + erff(val * 0.70710678118654752f));
        }
        if (SCALE) val *= sc;
        size_t off = (size_t)z * sC + (size_t)row * ldc + col;
        if (OBF16) {
          Cb[off] = (bf16_t)val;
        } else if (SCALE) {
          __builtin_nontemporal_store(val, Cf + off);   // logits: write-once
        } else {
          if (ACCUM) val += Cf[off];
          Cf[off] = val;
        }
      }
    }
  }
}

// ---------------------------------------------------------------- logits GEMM: single-buffer, 3 blk/CU
template <int ACT, bool ACCUM, bool SCALE, bool OBF16, bool SWZ>
__global__ __launch_bounds__(256, 3) void mm_k(
    const bf16_t* __restrict__ A, const bf16_t* __restrict__ B, void* __restrict__ Cv,
    const float* __restrict__ bias, int K, int lda, int ldb, int ldc,
    long long sA, long long sB, long long sC,
    const float* __restrict__ scale_ptr, float scale_const,
    float* __restrict__ o0, float* __restrict__ o1) {
  __shared__ bf16_t As[128 * 64];
  __shared__ bf16_t Bs[128 * 64];
  const int z = blockIdx.z;
  int ntile, mtile;
  if (SWZ) {
    int nwg = gridDim.x * gridDim.y;           // must be %8==0 (logits: 4000)
    int orig = blockIdx.y * gridDim.x + blockIdx.x;
    int q = nwg >> 3;
    int id = (orig & 7) * q + (orig >> 3);     // bijective XCD chunking
    mtile = id % gridDim.y;
    ntile = id / gridDim.y;
  } else {
    ntile = blockIdx.x;
    mtile = blockIdx.y;
  }
  const int bm = mtile * 128, bn = ntile * 128;
  A += (size_t)z * sA;
  B += (size_t)z * sB;
  const int tid = threadIdx.x, w = tid >> 6, l = tid & 63;
  const int wm = (w >> 1) * 64, wn = (w & 1) * 64;
  const int l15 = l & 15, lhi = l >> 4;

  int rS[4], koS[4];
#pragma unroll
  for (int i = 0; i < 4; ++i) {
    int c = tid + i * 256;
    int r = c >> 3, kb = (c & 7) << 4;
    rS[i] = r;
    koS[i] = (kb ^ ((r & 7) << 4)) >> 1;   // inverse-swz source element offset
  }
  const bf16_t* Ab = A + (size_t)bm * lda;
  const bf16_t* Bb = B + (size_t)bn * ldb;

  f32x4 acc[4][4] = {};
  for (int k0 = 0; k0 < K; k0 += 64) {
#pragma unroll
    for (int i = 0; i < 4; ++i) {
      __builtin_amdgcn_global_load_lds(
          (const __attribute__((address_space(1))) void*)(Ab + (size_t)rS[i] * lda + k0 + koS[i]),
          (__attribute__((address_space(3))) void*)(As + ((size_t)w * 64 + i * 256) * 8), 16, 0, 0);
    }
#pragma unroll
    for (int i = 0; i < 4; ++i) {
      __builtin_amdgcn_global_load_lds(
          (const __attribute__((address_space(1))) void*)(Bb + (size_t)rS[i] * ldb + k0 + koS[i]),
          (__attribute__((address_space(3))) void*)(Bs + ((size_t)w * 64 + i * 256) * 8), 16, 0, 0);
    }
    __syncthreads();
    bf16x8 af[2][4], bf_[2][4];
#pragma unroll
    for (int h = 0; h < 2; ++h) {
#pragma unroll
      for (int m = 0; m < 4; ++m) {
        int row = wm + m * 16 + l15;
        af[h][m] = *(const bf16x8*)(As + swz_eoff(row, (h << 6) | (lhi << 4)));
        int col = wn + m * 16 + l15;
        bf_[h][m] = *(const bf16x8*)(Bs + swz_eoff(col, (h << 6) | (lhi << 4)));
      }
    }
#pragma unroll
    for (int h = 0; h < 2; ++h)
#pragma unroll
      for (int m = 0; m < 4; ++m)
#pragma unroll
        for (int n = 0; n < 4; ++n)
          acc[m][n] = __builtin_amdgcn_mfma_f32_16x16x32_bf16(af[h][m], bf_[h][n], acc[m][n], 0, 0, 0);
    __syncthreads();
  }
  float sc = SCALE ? scale_const * scale_ptr[0] : 1.f;
  mm_epi<ACT, ACCUM, SCALE, OBF16>(acc, bm, bn, wm, wn, lhi, l15, Cv, bias, ldc, sC, z, sc, o0, o1);
}

// ---------------------------------------------------------------- small GEMM: 2-phase dbuf (grid-starved regime)
template <int ACT, bool ACCUM, bool OBF16>
__global__ __launch_bounds__(256, 2) void mms_k(
    const bf16_t* __restrict__ A, const bf16_t* __restrict__ B, void* __restrict__ Cv,
    const float* __restrict__ bias, int K, int lda, int ldb, int ldc,
    long long sA, long long sB, long long sC,
    float* __restrict__ o0, float* __restrict__ o1) {
  __shared__ bf16_t As[2 * 128 * 64];
  __shared__ bf16_t Bs[2 * 128 * 64];
  const int z = blockIdx.z;
  const int bm = blockIdx.y * 128, bn = blockIdx.x * 128;
  A += (size_t)z * sA;
  B += (size_t)z * sB;
  const int tid = threadIdx.x, w = tid >> 6, l = tid & 63;
  const int wm = (w >> 1) * 64, wn = (w & 1) * 64;
  const int l15 = l & 15, lhi = l >> 4;

  int rS[4], koS[4];
#pragma unroll
  for (int i = 0; i < 4; ++i) {
    int c = tid + i * 256;
    int r = c >> 3, kb = (c & 7) << 4;
    rS[i] = r;
    koS[i] = (kb ^ ((r & 7) << 4)) >> 1;
  }
  const bf16_t* Ab = A + (size_t)bm * lda;
  const bf16_t* Bb = B + (size_t)bn * ldb;

  auto STAGE = [&](int buf, int k0) {
    bf16_t* Ad = As + buf * 8192;
    bf16_t* Bd = Bs + buf * 8192;
#pragma unroll
    for (int i = 0; i < 4; ++i)
      __builtin_amdgcn_global_load_lds(
          (const __attribute__((address_space(1))) void*)(Ab + (size_t)rS[i] * lda + k0 + koS[i]),
          (__attribute__((address_space(3))) void*)(Ad + ((size_t)w * 64 + i * 256) * 8), 16, 0, 0);
#pragma unroll
    for (int i = 0; i < 4; ++i)
      __builtin_amdgcn_global_load_lds(
          (const __attribute__((address_space(1))) void*)(Bb + (size_t)rS[i] * ldb + k0 + koS[i]),
          (__attribute__((address_space(3))) void*)(Bd + ((size_t)w * 64 + i * 256) * 8), 16, 0, 0);
  };

  f32x4 acc[4][4] = {};
  const int nt = K >> 6;
  STAGE(0, 0);
  __syncthreads();
  int cur = 0;
  for (int t = 0; t < nt; ++t) {
    if (t + 1 < nt) STAGE(cur ^ 1, (t + 1) << 6);   // in flight during compute below
    const bf16_t* Ar = As + cur * 8192;
    const bf16_t* Br = Bs + cur * 8192;
    bf16x8 af[2][4], bf_[2][4];
#pragma unroll
    for (int h = 0; h < 2; ++h) {
#pragma unroll
      for (int m = 0; m < 4; ++m) {
        int row = wm + m * 16 + l15;
        af[h][m] = *(const bf16x8*)(Ar + swz_eoff(row, (h << 6) | (lhi << 4)));
        int col = wn + m * 16 + l15;
        bf_[h][m] = *(const bf16x8*)(Br + swz_eoff(col, (h << 6) | (lhi << 4)));
      }
    }
#pragma unroll
    for (int h = 0; h < 2; ++h)
#pragma unroll
      for (int m = 0; m < 4; ++m)
#pragma unroll
        for (int n = 0; n < 4; ++n)
          acc[m][n] = __builtin_amdgcn_mfma_f32_16x16x32_bf16(af[h][m], bf_[h][n], acc[m][n], 0, 0, 0);
    __syncthreads();
    cur ^= 1;
  }
  mm_epi<ACT, ACCUM, false, OBF16>(acc, bm, bn, wm, wn, lhi, l15, Cv, bias, ldc, sC, z, 1.f, o0, o1);
}

// ---------------------------------------------------------------- fused attention: direct-fragment GEMMs
// grid (3, B): role 0/1 = q-tile: reads = decayed(q@k^T) @ v ; role 2 = states = vtw@kt^T
// q/k/vt/vtw/kt are L2-resident -> load MFMA fragments straight from global (no staging drains).
__global__ __launch_bounds__(256) void attn_k(
    const bf16_t* __restrict__ qb, const bf16_t* __restrict__ kb,
    const bf16_t* __restrict__ vt, const bf16_t* __restrict__ vtw, const bf16_t* __restrict__ kt,
    const float* __restrict__ gwp, const float* __restrict__ cp,
    bf16_t* __restrict__ rd, float* __restrict__ states) {
  __shared__ bf16_t Ps[128 * 256];
  const int role = blockIdx.x, b = blockIdx.y;
  const int tid = threadIdx.x, w = tid >> 6, l = tid & 63;
  const int wm = (w >> 1) * 64, wn = (w & 1) * 64;
  const int l15 = l & 15, lhi = l >> 4;

  if (role == 2) {
    // states = vtw @ kt^T  (128x128, K=256) — pure register GEMM
    const bf16_t* Ab = vtw + (size_t)b * Mc * Tc;
    const bf16_t* Bb = kt + (size_t)b * Mc * Tc;
    f32x4 acc[4][4] = {};
#pragma unroll
    for (int ks = 0; ks < 4; ++ks) {
#pragma unroll
      for (int h = 0; h < 2; ++h) {
        int ko = ks * 64 + h * 32 + lhi * 8;
        bf16x8 af[4], bf_[4];
#pragma unroll
        for (int m = 0; m < 4; ++m)
          af[m] = *(const bf16x8*)(Ab + (size_t)(wm + m * 16 + l15) * Tc + ko);
#pragma unroll
        for (int n = 0; n < 4; ++n)
          bf_[n] = *(const bf16x8*)(Bb + (size_t)(wn + n * 16 + l15) * Tc + ko);
#pragma unroll
        for (int m = 0; m < 4; ++m)
#pragma unroll
          for (int n = 0; n < 4; ++n)
            acc[m][n] = __builtin_amdgcn_mfma_f32_16x16x32_bf16(af[m], bf_[n], acc[m][n], 0, 0, 0);
      }
    }
#pragma unroll
    for (int m = 0; m < 4; ++m)
#pragma unroll
      for (int n = 0; n < 4; ++n)
#pragma unroll
        for (int q = 0; q < 4; ++q) {
          int row = wm + m * 16 + lhi * 4 + q;
          int col = wn + n * 16 + l15;
          __builtin_nontemporal_store(acc[m][n][q], states + ((size_t)b * Mc + row) * Mc + col);
        }
    return;
  }

  const int q0 = role * 128;
  const bf16_t* Aq = qb + (size_t)(b * Tc + q0) * Mc;
  // ---- P phase: P[t][s] = decay(q_t . k_s), K=128, direct frags ----
#pragma unroll 1
  for (int nt2 = 0; nt2 < 2; ++nt2) {
    const bf16_t* Bk = kb + (size_t)(b * Tc + nt2 * 128) * Mc;
    f32x4 acc[4][4] = {};
#pragma unroll
    for (int kk = 0; kk < 2; ++kk) {
#pragma unroll
      for (int h = 0; h < 2; ++h) {
        int ko = kk * 64 + h * 32 + lhi * 8;
        bf16x8 af[4], bf_[4];
#pragma unroll
        for (int m = 0; m < 4; ++m)
          af[m] = *(const bf16x8*)(Aq + (size_t)(wm + m * 16 + l15) * Mc + ko);
#pragma unroll
        for (int n = 0; n < 4; ++n)
          bf_[n] = *(const bf16x8*)(Bk + (size_t)(wn + n * 16 + l15) * Mc + ko);
#pragma unroll
        for (int m = 0; m < 4; ++m)
#pragma unroll
          for (int n = 0; n < 4; ++n)
            acc[m][n] = __builtin_amdgcn_mfma_f32_16x16x32_bf16(af[m], bf_[n], acc[m][n], 0, 0, 0);
      }
    }
#pragma unroll
    for (int m = 0; m < 4; ++m)
#pragma unroll
      for (int n = 0; n < 4; ++n)
#pragma unroll
        for (int q = 0; q < 4; ++q) {
          int tr = wm + m * 16 + lhi * 4 + q;          // local t row (0..127)
          int scol = nt2 * 128 + wn + n * 16 + l15;    // s (0..255)
          int tg = q0 + tr;
          float val = acc[m][n][q];
          if (scol < tg)
            val *= gwp[b * Tc + scol] * expf(cp[b * Tc + tg - 1] - cp[b * Tc + scol]);
          else
            val = 0.f;
          int byte = (scol * 2) ^ ((tr & 7) << 4);
          Ps[tr * 256 + (byte >> 1)] = (bf16_t)val;
        }
  }
  __syncthreads();   // P complete
  // ---- PV: reads = P @ vt^T  (K=256), A from Ps (swizzled), B direct from global ----
  {
    const bf16_t* Bb = vt + (size_t)b * Mc * Tc;
    f32x4 acc[4][4] = {};
#pragma unroll
    for (int ks = 0; ks < 4; ++ks) {
#pragma unroll
      for (int h = 0; h < 2; ++h) {
        bf16x8 af[4], bf_[4];
#pragma unroll
        for (int m = 0; m < 4; ++m) {
          int row = wm + m * 16 + l15;
          int byteA = (ks * 128 + h * 64 + lhi * 16) ^ ((row & 7) << 4);
          af[m] = *(const bf16x8*)(Ps + row * 256 + (byteA >> 1));
        }
        int ko = ks * 64 + h * 32 + lhi * 8;
#pragma unroll
        for (int n = 0; n < 4; ++n)
          bf_[n] = *(const bf16x8*)(Bb + (size_t)(wn + n * 16 + l15) * Tc + ko);
#pragma unroll
        for (int m = 0; m < 4; ++m)
#pragma unroll
          for (int n = 0; n < 4; ++n)
            acc[m][n] = __builtin_amdgcn_mfma_f32_16x16x32_bf16(af[m], bf_[n], acc[m][n], 0, 0, 0);
      }
    }
#pragma unroll
    for (int m = 0; m < 4; ++m)
#pragma unroll
      for (int n = 0; n < 4; ++n)
#pragma unroll
        for (int q = 0; q < 4; ++q) {
          int row = wm + m * 16 + lhi * 4 + q;
          int col = wn + n * 16 + l15;
          rd[(size_t)(b * Tc + q0 + row) * Mc + col] = (bf16_t)acc[m][n][q];
        }
  }
}

// ---------------------------------------------------------------- launcher
extern "C" void kernel_launch(void* const* d_in, const int* in_sizes, int n_in,
                              void* d_out, int out_size, void* d_ws, size_t ws_size,
                              hipStream_t stream) {
  const int* idx = (const int*)d_in[0];
  const float* center = (const float*)d_in[1];
  // d_in[2] offset: dead code (x = (b_min+b_max)/2 = center)
  const float* wk = (const float*)d_in[3];
  const float* bk = (const float*)d_in[4];
  const float* wq = (const float*)d_in[5];
  const float* bq = (const float*)d_in[6];
  const float* wv = (const float*)d_in[7];
  const float* bv = (const float*)d_in[8];
  const float* wo = (const float*)d_in[9];
  const float* bo = (const float*)d_in[10];
  const float* wgw = (const float*)d_in[11];
  const float* bgw = (const float*)d_in[12];
  const float* wgf = (const float*)d_in[13];
  const float* bgf = (const float*)d_in[14];
  const float* ln1_g = (const float*)d_in[15];
  const float* ln1_b = (const float*)d_in[16];
  const float* ln2_g = (const float*)d_in[17];
  const float* ln2_b = (const float*)d_in[18];
  const float* w1 = (const float*)d_in[19];
  const float* b1 = (const float*)d_in[20];
  const float* w2 = (const float*)d_in[21];
  const float* b2 = (const float*)d_in[22];
  const float* lnf_g = (const float*)d_in[23];
  const float* lnf_b = (const float*)d_in[24];
  const float* logit_scale = (const float*)d_in[25];

  float* logits = (float*)d_out;                     // [R, V] fp32
  float* states = logits + (size_t)Rc * Vc;          // [L, B, M, M] fp32

  char* p = (char*)d_ws;
  auto alloc = [&](size_t bytes) -> char* {
    char* r = p;
    p += (bytes + 255) & ~(size_t)255;
    return r;
  };
  float* x    = (float*)alloc((size_t)Rc * Dc * 4);
  float* kqv  = (float*)alloc((size_t)Rc * 384 * 4);
  float* gwb  = (float*)alloc(Rc * 4);
  float* gfb  = (float*)alloc(Rc * 4);
  float* cb   = (float*)alloc(Rc * 4);
  float* bkqv = (float*)alloc(Lc * 512 * 4);
  float* part = (float*)alloc((size_t)2 * Rc * Dc * 4);   // split-K partials for w2
  bf16_t* xn_bf   = (bf16_t*)alloc((size_t)Rc * Dc * 2);
  bf16_t* h1_bf   = (bf16_t*)alloc((size_t)Rc * Hc * 2);
  bf16_t* k_bf    = (bf16_t*)alloc((size_t)Rc * Mc * 2);
  bf16_t* q_bf    = (bf16_t*)alloc((size_t)Rc * Mc * 2);
  bf16_t* rd_bf   = (bf16_t*)alloc((size_t)Rc * Mc * 2);
  bf16_t* kt_bf   = (bf16_t*)alloc((size_t)Bc * Mc * Tc * 2);
  bf16_t* vt_bf   = (bf16_t*)alloc((size_t)Bc * Mc * Tc * 2);
  bf16_t* vtw_bf  = (bf16_t*)alloc((size_t)Bc * Mc * Tc * 2);
  bf16_t* cen_bf  = (bf16_t*)alloc((size_t)Vc * Dc * 2);
  bf16_t* w1_bf   = (bf16_t*)alloc((size_t)Lc * Hc * Dc * 2);
  bf16_t* w2_bf   = (bf16_t*)alloc((size_t)Lc * Dc * Hc * 2);
  bf16_t* wo_bf   = (bf16_t*)alloc((size_t)Lc * Dc * Mc * 2);
  bf16_t* wkqv_bf = (bf16_t*)alloc((size_t)Lc * 512 * Dc * 2);

  cvtall_k<<<12224, 256, 0, stream>>>(center, cen_bf, w1, w1_bf, w2, w2_bf, wo, wo_bf);
  packkqv_k<<<Lc * 512, 128, 0, stream>>>(wk, wq, wv, wgw, wgf, wkqv_bf);
  packb_k<<<(Lc * 512 + 255) / 256, 256, 0, stream>>>(bk, bq, bv, bgw, bgf, bkqv);

  // gather + ln1(layer 0) fused
  gl_k<<<Rc, 64, 0, stream>>>(idx, center, ln1_g, ln1_b, x, xn_bf);

  const long long zero = 0;
  for (int l = 0; l < Lc; ++l) {
    // kqv+gw+gf = xn @ [wk;wq;wv;wgw;wgf]^T + b  (tanh on v, sigmoid on gw/gf)
    mms_k<A_KQV, false, false><<<dim3(4, 16, 1), 256, 0, stream>>>(
        xn_bf, wkqv_bf + (size_t)l * 512 * Dc, kqv, bkqv + l * 512,
        Dc, Dc, Dc, 384, zero, zero, zero, gwb, gfb);

    // fused scan + l2norm + transposes (64 blocks)
    prep_k<<<dim3(Tc / 32, Bc), 256, 0, stream>>>(kqv, gwb, gfb, cb, k_bf, q_bf, kt_bf, vt_bf, vtw_bf);

    // fused P(decay) + PV + states (direct-fragment)
    attn_k<<<dim3(3, Bc), 256, 0, stream>>>(q_bf, k_bf, vt_bf, vtw_bf, kt_bf, gwb, cb,
                                            rd_bf, states + (size_t)l * Bc * Mc * Mc);

    // x += reads @ wo^T + bo
    mms_k<A_NONE, true, false><<<dim3(4, 16, 1), 256, 0, stream>>>(
        rd_bf, wo_bf + (size_t)l * Dc * Mc, x, bo + (size_t)l * Dc,
        Mc, Mc, Mc, Dc, zero, zero, zero, nullptr, nullptr);

    ln_k<<<Rc, 64, 0, stream>>>(x, ln2_g + (size_t)l * Dc, ln2_b + (size_t)l * Dc, xn_bf);

    // h1 = gelu(xn @ w1^T + b1) -> bf16
    mms_k<A_GELU, false, true><<<dim3(16, 16, 1), 256, 0, stream>>>(
        xn_bf, w1_bf + (size_t)l * Hc * Dc, h1_bf, b1 + (size_t)l * Hc,
        Dc, Dc, Dc, Hc, zero, zero, zero, nullptr, nullptr);

    // w2 split-K=2: partials
    mms_k<A_NONE, false, false><<<dim3(4, 16, 2), 256, 0, stream>>>(
        h1_bf, w2_bf + (size_t)l * Dc * Hc, part, nullptr,
        Hc / 2, Hc, Hc, Dc, (long long)(Hc / 2), (long long)(Hc / 2), (long long)Rc * Dc,
        nullptr, nullptr);

    // x += partials + b2 ; xn = LN(x) with next layer's ln1 (or lnf after last layer)
    const float* ng = (l < Lc - 1) ? ln1_g + (size_t)(l + 1) * Dc : lnf_g;
    const float* nb = (l < Lc - 1) ? ln1_b + (size_t)(l + 1) * Dc : lnf_b;
    redln_k<<<Rc, 64, 0, stream>>>(part, b2 + (size_t)l * Dc, x, ng, nb, xn_bf);
  }

  // logits = (xn @ center^T) * logit_scale/sqrt(512)   (XCD-swizzled, 4000 blocks)
  mm_k<A_NONE, false, true, false, true><<<dim3(250, 16, 1), 256, 0, stream>>>(
      xn_bf, cen_bf, logits, nullptr, Dc, Dc, Dc, Vc, zero, zero, zero,
      logit_scale, 0.044194173824159223f, nullptr, nullptr);
}

// Round 7
// 630.621 us; speedup vs baseline: 1.1259x; 1.1259x over previous
//
#include <hip/hip_runtime.h>
#include <math.h>

// Problem constants
constexpr int Bc = 8, Tc = 256, Dc = 512, Mc = 128, Lc = 4, Vc = 32000;
constexpr int Rc = Bc * Tc;          // 2048 rows
constexpr int Hc = 4 * Dc;           // 2048 hidden

typedef __bf16 bf16_t;
typedef __bf16 bf16x8 __attribute__((ext_vector_type(8)));
typedef float f32x4 __attribute__((ext_vector_type(4)));
static_assert(sizeof(bf16x8) == 16, "bf16x8 must be 16B");

#define DEV __device__ __forceinline__

DEV float wred64(float x) {
#pragma unroll
  for (int o = 32; o; o >>= 1) x += __shfl_xor(x, o);
  return x;
}

// ---------------------------------------------------------------- merged preamble:
// blocks [0,12224): fp32->bf16 cvt (center 8000 | w1 2048 | w2 2048 | wo 128; 2048 elems/blk)
// blocks [12224,13248): pack wkqv rows (2 rows/blk)
// blocks [13248,13256): pack bkqv
// blocks [13256,13768): gather + ln1(layer0) (4 rows/blk, one per wave)
__global__ __launch_bounds__(256) void pre_k(
    const float* __restrict__ center, bf16_t* __restrict__ cen_bf,
    const float* __restrict__ w1, bf16_t* __restrict__ w1_bf,
    const float* __restrict__ w2, bf16_t* __restrict__ w2_bf,
    const float* __restrict__ wo, bf16_t* __restrict__ wo_bf,
    const float* __restrict__ wk, const float* __restrict__ wq,
    const float* __restrict__ wv, const float* __restrict__ wgw,
    const float* __restrict__ wgf, bf16_t* __restrict__ wkqv_bf,
    const float* __restrict__ bk, const float* __restrict__ bq,
    const float* __restrict__ bv, const float* __restrict__ bgw,
    const float* __restrict__ bgf, float* __restrict__ bkqv,
    const int* __restrict__ idx, const float* __restrict__ g1,
    const float* __restrict__ b1, float* __restrict__ x,
    bf16_t* __restrict__ xn) {
  int blk = blockIdx.x, t = threadIdx.x;
  if (blk < 12224) {
    const float* src; bf16_t* dst; int base;
    if (blk < 8000)       { src = center; dst = cen_bf; base = blk; }
    else if (blk < 10048) { src = w1; dst = w1_bf; base = blk - 8000; }
    else if (blk < 12096) { src = w2; dst = w2_bf; base = blk - 10048; }
    else                  { src = wo; dst = wo_bf; base = blk - 12096; }
    size_t i = (size_t)base * 2048 + (size_t)t * 8;
    float4 a = *(const float4*)(src + i);
    float4 b = *(const float4*)(src + i + 4);
    bf16_t o[8] = {(bf16_t)a.x, (bf16_t)a.y, (bf16_t)a.z, (bf16_t)a.w,
                   (bf16_t)b.x, (bf16_t)b.y, (bf16_t)b.z, (bf16_t)b.w};
    *(bf16x8*)(dst + i) = *(bf16x8*)o;
  } else if (blk < 13248) {
    int row = (blk - 12224) * 2 + (t >> 7);
    int t7 = t & 127;
    int lyr = row >> 9, o = row & 511;
    const float* src = nullptr;
    if (o < 128) src = wk + ((size_t)lyr * 128 + o) * Dc;
    else if (o < 256) src = wq + ((size_t)lyr * 128 + (o - 128)) * Dc;
    else if (o < 384) src = wv + ((size_t)lyr * 128 + (o - 256)) * Dc;
    else if (o == 384) src = wgw + (size_t)lyr * Dc;
    else if (o == 385) src = wgf + (size_t)lyr * Dc;
    bf16_t* dst = wkqv_bf + (size_t)row * Dc + t7 * 4;
    if (src) {
      float4 v = ((const float4*)src)[t7];
      dst[0] = (bf16_t)v.x; dst[1] = (bf16_t)v.y; dst[2] = (bf16_t)v.z; dst[3] = (bf16_t)v.w;
    } else {
      dst[0] = dst[1] = dst[2] = dst[3] = (bf16_t)0.f;
    }
  } else if (blk < 13256) {
    int i = (blk - 13248) * 256 + t;
    int lyr = i >> 9, o = i & 511;
    float v = 0.f;
    if (o < 128) v = bk[lyr * 128 + o];
    else if (o < 256) v = bq[lyr * 128 + o - 128];
    else if (o < 384) v = bv[lyr * 128 + o - 256];
    else if (o == 384) v = bgw[lyr];
    else if (o == 385) v = bgf[lyr];
    bkqv[i] = v;
  } else {
    int r = (blk - 13256) * 4 + (t >> 6);
    int t6 = t & 63;
    const float4* row = (const float4*)(center + (size_t)idx[r] * Dc);
    float xv[8];
    *(float4*)&xv[0] = row[2 * t6];
    *(float4*)&xv[4] = row[2 * t6 + 1];
    float4* xrow = (float4*)(x + (size_t)r * Dc);
    xrow[2 * t6] = *(float4*)&xv[0];
    xrow[2 * t6 + 1] = *(float4*)&xv[4];
    float s = 0.f, ss = 0.f;
#pragma unroll
    for (int e = 0; e < 8; ++e) { s += xv[e]; ss += xv[e] * xv[e]; }
    s = wred64(s); ss = wred64(ss);
    float mu = s * (1.f / Dc);
    float inv = 1.f / sqrtf(ss * (1.f / Dc) - mu * mu + 1e-5f);
    float gg[8], bb[8];
    *(float4*)&gg[0] = ((const float4*)g1)[2 * t6];
    *(float4*)&gg[4] = ((const float4*)g1)[2 * t6 + 1];
    *(float4*)&bb[0] = ((const float4*)b1)[2 * t6];
    *(float4*)&bb[4] = ((const float4*)b1)[2 * t6 + 1];
    bf16_t ob[8];
#pragma unroll
    for (int e = 0; e < 8; ++e) ob[e] = (bf16_t)((xv[e] - mu) * inv * gg[e] + bb[e]);
    *(bf16x8*)(xn + (size_t)r * Dc + t6 * 8) = *(bf16x8*)ob;
  }
}

// ---------------------------------------------------------------- LayerNorm -> bf16 (ln2)
__global__ __launch_bounds__(64) void ln_k(const float* __restrict__ in,
                                           const float* __restrict__ g,
                                           const float* __restrict__ b,
                                           bf16_t* __restrict__ out) {
  int r = blockIdx.x, t = threadIdx.x;
  const float4* row = (const float4*)(in + (size_t)r * Dc);
  float xv[8];
  *(float4*)&xv[0] = row[2 * t];
  *(float4*)&xv[4] = row[2 * t + 1];
  float s = 0.f, ss = 0.f;
#pragma unroll
  for (int e = 0; e < 8; ++e) { s += xv[e]; ss += xv[e] * xv[e]; }
  s = wred64(s); ss = wred64(ss);
  float mu = s * (1.f / Dc);
  float inv = 1.f / sqrtf(ss * (1.f / Dc) - mu * mu + 1e-5f);
  float gg[8], bb[8];
  *(float4*)&gg[0] = ((const float4*)g)[2 * t];
  *(float4*)&gg[4] = ((const float4*)g)[2 * t + 1];
  *(float4*)&bb[0] = ((const float4*)b)[2 * t];
  *(float4*)&bb[4] = ((const float4*)b)[2 * t + 1];
  bf16_t ob[8];
#pragma unroll
  for (int e = 0; e < 8; ++e) ob[e] = (bf16_t)((xv[e] - mu) * inv * gg[e] + bb[e]);
  *(bf16x8*)(out + (size_t)r * Dc + t * 8) = *(bf16x8*)ob;
}

// ---------------------------------------------------------------- split-K reduce + bias + residual + LN
__global__ __launch_bounds__(64) void redln_k(const float* __restrict__ part,
                                              const float* __restrict__ bias,
                                              float* __restrict__ x,
                                              const float* __restrict__ g,
                                              const float* __restrict__ b,
                                              bf16_t* __restrict__ xn) {
  int r = blockIdx.x, t = threadIdx.x;
  const float4* xr = (const float4*)(x + (size_t)r * Dc);
  const float4* p0 = (const float4*)(part + (size_t)r * Dc);
  const float4* p1 = (const float4*)(part + (size_t)(Rc + r) * Dc);
  const float4* bb4 = (const float4*)bias;
  float xv[8];
#pragma unroll
  for (int j = 0; j < 2; ++j) {
    float4 a = xr[2 * t + j], q = p0[2 * t + j], w = p1[2 * t + j], c = bb4[2 * t + j];
    xv[4 * j + 0] = a.x + q.x + w.x + c.x;
    xv[4 * j + 1] = a.y + q.y + w.y + c.y;
    xv[4 * j + 2] = a.z + q.z + w.z + c.z;
    xv[4 * j + 3] = a.w + q.w + w.w + c.w;
  }
  float4* xw = (float4*)(x + (size_t)r * Dc);
  xw[2 * t] = *(float4*)&xv[0];
  xw[2 * t + 1] = *(float4*)&xv[4];
  float s = 0.f, ss = 0.f;
#pragma unroll
  for (int e = 0; e < 8; ++e) { s += xv[e]; ss += xv[e] * xv[e]; }
  s = wred64(s); ss = wred64(ss);
  float mu = s * (1.f / Dc);
  float inv = 1.f / sqrtf(ss * (1.f / Dc) - mu * mu + 1e-5f);
  float gg[8], bv[8];
  *(float4*)&gg[0] = ((const float4*)g)[2 * t];
  *(float4*)&gg[4] = ((const float4*)g)[2 * t + 1];
  *(float4*)&bv[0] = ((const float4*)b)[2 * t];
  *(float4*)&bv[4] = ((const float4*)b)[2 * t + 1];
  bf16_t ob[8];
#pragma unroll
  for (int e = 0; e < 8; ++e) ob[e] = (bf16_t)((xv[e] - mu) * inv * gg[e] + bv[e]);
  *(bf16x8*)(xn + (size_t)r * Dc + t * 8) = *(bf16x8*)ob;
}

// ---------------------------------------------------------------- MFMA helpers
DEV int swz_eoff(int row, int kbyte) {
  return row * 64 + ((kbyte ^ ((row & 7) << 4)) >> 1);
}

enum { A_NONE = 0, A_GELU = 2 };

// shared epilogue (plain GEMMs)
template <int ACT, bool ACCUM, bool SCALE, bool OBF16>
DEV void mm_epi(f32x4 (&acc)[4][4], int bm, int bn, int wm, int wn, int lhi, int l15,
                void* Cv, const float* bias, int ldc, long long sC, int z, float sc) {
  float* Cf = (float*)Cv;
  bf16_t* Cb = (bf16_t*)Cv;
#pragma unroll
  for (int m = 0; m < 4; ++m) {
#pragma unroll
    for (int n = 0; n < 4; ++n) {
#pragma unroll
      for (int q = 0; q < 4; ++q) {
        int row = bm + wm + m * 16 + lhi * 4 + q;   // C/D: col=lane&15, row=(lane>>4)*4+reg (m89)
        int col = bn + wn + n * 16 + l15;
        float val = acc[m][n][q];
        if (bias) val += bias[col];
        if (ACT == A_GELU) {
          val = 0.5f * val * (1.f + erff(val * 0.70710678118654752f));
        }
        if (SCALE) val *= sc;
        size_t off = (size_t)z * sC + (size_t)row * ldc + col;
        if (OBF16) {
          Cb[off] = (bf16_t)val;
        } else if (SCALE) {
          __builtin_nontemporal_store(val, Cf + off);   // logits: write-once
        } else {
          if (ACCUM) val += Cf[off];
          Cf[off] = val;
        }
      }
    }
  }
}

// ---------------------------------------------------------------- logits GEMM: single-buffer, 3 blk/CU
template <int ACT, bool ACCUM, bool SCALE, bool OBF16, bool SWZ>
__global__ __launch_bounds__(256, 3) void mm_k(
    const bf16_t* __restrict__ A, const bf16_t* __restrict__ B, void* __restrict__ Cv,
    const float* __restrict__ bias, int K, int lda, int ldb, int ldc,
    long long sA, long long sB, long long sC,
    const float* __restrict__ scale_ptr, float scale_const) {
  __shared__ bf16_t As[128 * 64];
  __shared__ bf16_t Bs[128 * 64];
  const int z = blockIdx.z;
  int ntile, mtile;
  if (SWZ) {
    int nwg = gridDim.x * gridDim.y;           // must be %8==0 (logits: 4000)
    int orig = blockIdx.y * gridDim.x + blockIdx.x;
    int q = nwg >> 3;
    int id = (orig & 7) * q + (orig >> 3);     // bijective XCD chunking
    mtile = id % gridDim.y;
    ntile = id / gridDim.y;
  } else {
    ntile = blockIdx.x;
    mtile = blockIdx.y;
  }
  const int bm = mtile * 128, bn = ntile * 128;
  A += (size_t)z * sA;
  B += (size_t)z * sB;
  const int tid = threadIdx.x, w = tid >> 6, l = tid & 63;
  const int wm = (w >> 1) * 64, wn = (w & 1) * 64;
  const int l15 = l & 15, lhi = l >> 4;

  int rS[4], koS[4];
#pragma unroll
  for (int i = 0; i < 4; ++i) {
    int c = tid + i * 256;
    int r = c >> 3, kb = (c & 7) << 4;
    rS[i] = r;
    koS[i] = (kb ^ ((r & 7) << 4)) >> 1;   // inverse-swz source element offset
  }
  const bf16_t* Ab = A + (size_t)bm * lda;
  const bf16_t* Bb = B + (size_t)bn * ldb;

  f32x4 acc[4][4] = {};
  for (int k0 = 0; k0 < K; k0 += 64) {
#pragma unroll
    for (int i = 0; i < 4; ++i) {
      __builtin_amdgcn_global_load_lds(
          (const __attribute__((address_space(1))) void*)(Ab + (size_t)rS[i] * lda + k0 + koS[i]),
          (__attribute__((address_space(3))) void*)(As + ((size_t)w * 64 + i * 256) * 8), 16, 0, 0);
    }
#pragma unroll
    for (int i = 0; i < 4; ++i) {
      __builtin_amdgcn_global_load_lds(
          (const __attribute__((address_space(1))) void*)(Bb + (size_t)rS[i] * ldb + k0 + koS[i]),
          (__attribute__((address_space(3))) void*)(Bs + ((size_t)w * 64 + i * 256) * 8), 16, 0, 0);
    }
    __syncthreads();
    bf16x8 af[2][4], bf_[2][4];
#pragma unroll
    for (int h = 0; h < 2; ++h) {
#pragma unroll
      for (int m = 0; m < 4; ++m) {
        int row = wm + m * 16 + l15;
        af[h][m] = *(const bf16x8*)(As + swz_eoff(row, (h << 6) | (lhi << 4)));
        int col = wn + m * 16 + l15;
        bf_[h][m] = *(const bf16x8*)(Bs + swz_eoff(col, (h << 6) | (lhi << 4)));
      }
    }
#pragma unroll
    for (int h = 0; h < 2; ++h)
#pragma unroll
      for (int m = 0; m < 4; ++m)
#pragma unroll
        for (int n = 0; n < 4; ++n)
          acc[m][n] = __builtin_amdgcn_mfma_f32_16x16x32_bf16(af[h][m], bf_[h][n], acc[m][n], 0, 0, 0);
    __syncthreads();
  }
  float sc = SCALE ? scale_const * scale_ptr[0] : 1.f;
  mm_epi<ACT, ACCUM, SCALE, OBF16>(acc, bm, bn, wm, wn, lhi, l15, Cv, bias, ldc, sC, z, sc);
}

// ---------------------------------------------------------------- small GEMM: 2-phase dbuf
template <int ACT, bool ACCUM, bool OBF16>
__global__ __launch_bounds__(256, 2) void mms_k(
    const bf16_t* __restrict__ A, const bf16_t* __restrict__ B, void* __restrict__ Cv,
    const float* __restrict__ bias, int K, int lda, int ldb, int ldc,
    long long sA, long long sB, long long sC) {
  __shared__ bf16_t As[2 * 128 * 64];
  __shared__ bf16_t Bs[2 * 128 * 64];
  const int z = blockIdx.z;
  const int bm = blockIdx.y * 128, bn = blockIdx.x * 128;
  A += (size_t)z * sA;
  B += (size_t)z * sB;
  const int tid = threadIdx.x, w = tid >> 6, l = tid & 63;
  const int wm = (w >> 1) * 64, wn = (w & 1) * 64;
  const int l15 = l & 15, lhi = l >> 4;

  int rS[4], koS[4];
#pragma unroll
  for (int i = 0; i < 4; ++i) {
    int c = tid + i * 256;
    int r = c >> 3, kb = (c & 7) << 4;
    rS[i] = r;
    koS[i] = (kb ^ ((r & 7) << 4)) >> 1;
  }
  const bf16_t* Ab = A + (size_t)bm * lda;
  const bf16_t* Bb = B + (size_t)bn * ldb;

  auto STAGE = [&](int buf, int k0) {
    bf16_t* Ad = As + buf * 8192;
    bf16_t* Bd = Bs + buf * 8192;
#pragma unroll
    for (int i = 0; i < 4; ++i)
      __builtin_amdgcn_global_load_lds(
          (const __attribute__((address_space(1))) void*)(Ab + (size_t)rS[i] * lda + k0 + koS[i]),
          (__attribute__((address_space(3))) void*)(Ad + ((size_t)w * 64 + i * 256) * 8), 16, 0, 0);
#pragma unroll
    for (int i = 0; i < 4; ++i)
      __builtin_amdgcn_global_load_lds(
          (const __attribute__((address_space(1))) void*)(Bb + (size_t)rS[i] * ldb + k0 + koS[i]),
          (__attribute__((address_space(3))) void*)(Bd + ((size_t)w * 64 + i * 256) * 8), 16, 0, 0);
  };

  f32x4 acc[4][4] = {};
  const int nt = K >> 6;
  STAGE(0, 0);
  __syncthreads();
  int cur = 0;
  for (int t = 0; t < nt; ++t) {
    if (t + 1 < nt) STAGE(cur ^ 1, (t + 1) << 6);
    const bf16_t* Ar = As + cur * 8192;
    const bf16_t* Br = Bs + cur * 8192;
    bf16x8 af[2][4], bf_[2][4];
#pragma unroll
    for (int h = 0; h < 2; ++h) {
#pragma unroll
      for (int m = 0; m < 4; ++m) {
        int row = wm + m * 16 + l15;
        af[h][m] = *(const bf16x8*)(Ar + swz_eoff(row, (h << 6) | (lhi << 4)));
        int col = wn + m * 16 + l15;
        bf_[h][m] = *(const bf16x8*)(Br + swz_eoff(col, (h << 6) | (lhi << 4)));
      }
    }
#pragma unroll
    for (int h = 0; h < 2; ++h)
#pragma unroll
      for (int m = 0; m < 4; ++m)
#pragma unroll
        for (int n = 0; n < 4; ++n)
          acc[m][n] = __builtin_amdgcn_mfma_f32_16x16x32_bf16(af[h][m], bf_[h][n], acc[m][n], 0, 0, 0);
    __syncthreads();
    cur ^= 1;
  }
  mm_epi<ACT, ACCUM, false, OBF16>(acc, bm, bn, wm, wn, lhi, l15, Cv, bias, ldc, sC, z, 1.f);
}

// ---------------------------------------------------------------- kqv GEMM + fused prep epilogue
// grid (4,16): ntile 0=k,1=q,2=v,3=gates; mtile over 2048 rows (128 each).
// Epilogue: acc -> LDS fp32 tile -> l2norm (k,q) -> kb/qb row-major + kt/vt transposed bf16.
__global__ __launch_bounds__(256) void kqvprep_k(
    const bf16_t* __restrict__ A, const bf16_t* __restrict__ B,
    const float* __restrict__ bias,
    bf16_t* __restrict__ kb, bf16_t* __restrict__ qb,
    bf16_t* __restrict__ kt, bf16_t* __restrict__ vt,
    float* __restrict__ gwb, float* __restrict__ gfb) {
  __shared__ bf16_t As[2 * 128 * 64];
  __shared__ bf16_t Bs[2 * 128 * 64];
  __shared__ float tile[128 * 129];
  __shared__ float rno[128];
  const int ntile = blockIdx.x, mtile = blockIdx.y;
  const int bm = mtile * 128, bn = ntile * 128;
  const int tid = threadIdx.x, w = tid >> 6, l = tid & 63;
  const int wm = (w >> 1) * 64, wn = (w & 1) * 64;
  const int l15 = l & 15, lhi = l >> 4;

  int rS[4], koS[4];
#pragma unroll
  for (int i = 0; i < 4; ++i) {
    int c = tid + i * 256;
    int r = c >> 3, kbb = (c & 7) << 4;
    rS[i] = r;
    koS[i] = (kbb ^ ((r & 7) << 4)) >> 1;
  }
  const bf16_t* Ab = A + (size_t)bm * Dc;
  const bf16_t* Bb = B + (size_t)bn * Dc;

  auto STAGE = [&](int buf, int k0) {
    bf16_t* Ad = As + buf * 8192;
    bf16_t* Bd = Bs + buf * 8192;
#pragma unroll
    for (int i = 0; i < 4; ++i)
      __builtin_amdgcn_global_load_lds(
          (const __attribute__((address_space(1))) void*)(Ab + (size_t)rS[i] * Dc + k0 + koS[i]),
          (__attribute__((address_space(3))) void*)(Ad + ((size_t)w * 64 + i * 256) * 8), 16, 0, 0);
#pragma unroll
    for (int i = 0; i < 4; ++i)
      __builtin_amdgcn_global_load_lds(
          (const __attribute__((address_space(1))) void*)(Bb + (size_t)rS[i] * Dc + k0 + koS[i]),
          (__attribute__((address_space(3))) void*)(Bd + ((size_t)w * 64 + i * 256) * 8), 16, 0, 0);
  };

  f32x4 acc[4][4] = {};
  STAGE(0, 0);
  __syncthreads();
  int cur = 0;
  for (int t = 0; t < 8; ++t) {
    if (t + 1 < 8) STAGE(cur ^ 1, (t + 1) << 6);
    const bf16_t* Ar = As + cur * 8192;
    const bf16_t* Br = Bs + cur * 8192;
    bf16x8 af[2][4], bf_[2][4];
#pragma unroll
    for (int h = 0; h < 2; ++h) {
#pragma unroll
      for (int m = 0; m < 4; ++m) {
        int row = wm + m * 16 + l15;
        af[h][m] = *(const bf16x8*)(Ar + swz_eoff(row, (h << 6) | (lhi << 4)));
        int col = wn + m * 16 + l15;
        bf_[h][m] = *(const bf16x8*)(Br + swz_eoff(col, (h << 6) | (lhi << 4)));
      }
    }
#pragma unroll
    for (int h = 0; h < 2; ++h)
#pragma unroll
      for (int m = 0; m < 4; ++m)
#pragma unroll
        for (int n = 0; n < 4; ++n)
          acc[m][n] = __builtin_amdgcn_mfma_f32_16x16x32_bf16(af[h][m], bf_[h][n], acc[m][n], 0, 0, 0);
    __syncthreads();
    cur ^= 1;
  }

  // ---- epilogue ----
  if (ntile == 3) {   // gates: only local cols 0 (gw) and 1 (gf) matter
#pragma unroll
    for (int m = 0; m < 4; ++m)
#pragma unroll
      for (int n = 0; n < 4; ++n)
#pragma unroll
        for (int q = 0; q < 4; ++q) {
          int c = wn + n * 16 + l15;
          if (c <= 1) {
            int row = bm + wm + m * 16 + lhi * 4 + q;
            float val = acc[m][n][q] + bias[384 + c];
            if (c == 0) gwb[row] = 1.f / (1.f + expf(-val));
            else gfb[row] = 0.9f / (1.f + expf(-val));
          }
        }
    return;
  }
  // acc (+bias, tanh for v) -> fp32 LDS tile
#pragma unroll
  for (int m = 0; m < 4; ++m)
#pragma unroll
    for (int n = 0; n < 4; ++n)
#pragma unroll
      for (int q = 0; q < 4; ++q) {
        int row = wm + m * 16 + lhi * 4 + q;
        int col = wn + n * 16 + l15;
        float val = acc[m][n][q] + bias[ntile * 128 + col];
        if (ntile == 2) val = tanhf(val);
        tile[row * 129 + col] = val;
      }
  __syncthreads();

  const int b = bm >> 8;          // batch
  const int s0 = bm & 255;        // s offset within batch

  if (ntile <= 1) {               // per-row 1/||.||
    int row = tid >> 1, off = (tid & 1) * 64;
    float ss = 0.f;
#pragma unroll
    for (int e = 0; e < 64; ++e) { float v = tile[row * 129 + off + e]; ss += v * v; }
    ss += __shfl_xor(ss, 1);
    if (!(tid & 1)) rno[row] = 1.f / fmaxf(sqrtf(ss), 1e-12f);
    __syncthreads();
    // row-major normalized output
    float rn = rno[row];
    bf16_t* dst = (ntile == 0 ? kb : qb) + (size_t)(bm + row) * Mc + off;
#pragma unroll
    for (int j = 0; j < 8; ++j) {
      bf16_t o[8];
#pragma unroll
      for (int e = 0; e < 8; ++e) o[e] = (bf16_t)(tile[row * 129 + off + j * 8 + e] * rn);
      *(bf16x8*)(dst + j * 8) = *(bf16x8*)o;
    }
  }
  if (ntile == 0 || ntile == 2) { // transposed output (kt normalized, vt raw)
    int d = tid >> 1, s8 = (tid & 1) * 64;
    bf16_t* dst = (ntile == 0 ? kt : vt) + ((size_t)b * Mc + d) * Tc + s0 + s8;
#pragma unroll
    for (int j = 0; j < 8; ++j) {
      bf16_t o[8];
#pragma unroll
      for (int e = 0; e < 8; ++e) {
        int s = s8 + j * 8 + e;
        float v = tile[s * 129 + d];
        if (ntile == 0) v *= rno[s];
        o[e] = (bf16_t)v;
      }
      *(bf16x8*)(dst + j * 8) = *(bf16x8*)o;
    }
  }
}

// ---------------------------------------------------------------- fused attention (in-kernel decay scan)
// grid (3, B): role 0/1 = q-tile: reads = decayed(q@k^T) @ v ; role 2 = states = (wgt*v)@kt^T
__global__ __launch_bounds__(256) void attn_k(
    const bf16_t* __restrict__ qb, const bf16_t* __restrict__ kb,
    const bf16_t* __restrict__ vt, const bf16_t* __restrict__ kt,
    const float* __restrict__ gwb, const float* __restrict__ gfb,
    bf16_t* __restrict__ rd, float* __restrict__ states) {
  __shared__ bf16_t Ps[128 * 256];
  __shared__ float sc[Tc], sgw[Tc], sw[Tc];
  const int role = blockIdx.x, b = blockIdx.y;
  const int tid = threadIdx.x, w = tid >> 6, l = tid & 63;
  const int wm = (w >> 1) * 64, wn = (w & 1) * 64;
  const int l15 = l & 15, lhi = l >> 4;

  // decay prefix scan (redundant per block; 256 threads)
  sc[tid] = logf(gfb[b * Tc + tid]);
  sgw[tid] = gwb[b * Tc + tid];
  __syncthreads();
  for (int o = 1; o < Tc; o <<= 1) {
    float v = (tid >= o) ? sc[tid - o] : 0.f;
    __syncthreads();
    sc[tid] += v;
    __syncthreads();
  }
  sw[tid] = sgw[tid] * expf(sc[Tc - 1] - sc[tid]);
  __syncthreads();

  if (role == 2) {
    // states = (wgt*v) @ kt^T  (128x128, K=256); wgt applied in-register on A
    const bf16_t* Ab = vt + (size_t)b * Mc * Tc;
    const bf16_t* Bb = kt + (size_t)b * Mc * Tc;
    f32x4 acc[4][4] = {};
#pragma unroll
    for (int ks = 0; ks < 4; ++ks) {
#pragma unroll
      for (int h = 0; h < 2; ++h) {
        int ko = ks * 64 + h * 32 + lhi * 8;
        bf16x8 af[4], bf_[4];
#pragma unroll
        for (int m = 0; m < 4; ++m) {
          bf16x8 raw = *(const bf16x8*)(Ab + (size_t)(wm + m * 16 + l15) * Tc + ko);
          bf16_t sa[8];
#pragma unroll
          for (int e = 0; e < 8; ++e) sa[e] = (bf16_t)((float)raw[e] * sw[ko + e]);
          af[m] = *(bf16x8*)sa;
        }
#pragma unroll
        for (int n = 0; n < 4; ++n)
          bf_[n] = *(const bf16x8*)(Bb + (size_t)(wn + n * 16 + l15) * Tc + ko);
#pragma unroll
        for (int m = 0; m < 4; ++m)
#pragma unroll
          for (int n = 0; n < 4; ++n)
            acc[m][n] = __builtin_amdgcn_mfma_f32_16x16x32_bf16(af[m], bf_[n], acc[m][n], 0, 0, 0);
      }
    }
#pragma unroll
    for (int m = 0; m < 4; ++m)
#pragma unroll
      for (int n = 0; n < 4; ++n)
#pragma unroll
        for (int q = 0; q < 4; ++q) {
          int row = wm + m * 16 + lhi * 4 + q;
          int col = wn + n * 16 + l15;
          __builtin_nontemporal_store(acc[m][n][q], states + ((size_t)b * Mc + row) * Mc + col);
        }
    return;
  }

  const int q0 = role * 128;
  const bf16_t* Aq = qb + (size_t)(b * Tc + q0) * Mc;
  // ---- P phase ----
#pragma unroll 1
  for (int nt2 = 0; nt2 < 2; ++nt2) {
    const bf16_t* Bk = kb + (size_t)(b * Tc + nt2 * 128) * Mc;
    f32x4 acc[4][4] = {};
#pragma unroll
    for (int kk = 0; kk < 2; ++kk) {
#pragma unroll
      for (int h = 0; h < 2; ++h) {
        int ko = kk * 64 + h * 32 + lhi * 8;
        bf16x8 af[4], bf_[4];
#pragma unroll
        for (int m = 0; m < 4; ++m)
          af[m] = *(const bf16x8*)(Aq + (size_t)(wm + m * 16 + l15) * Mc + ko);
#pragma unroll
        for (int n = 0; n < 4; ++n)
          bf_[n] = *(const bf16x8*)(Bk + (size_t)(wn + n * 16 + l15) * Mc + ko);
#pragma unroll
        for (int m = 0; m < 4; ++m)
#pragma unroll
          for (int n = 0; n < 4; ++n)
            acc[m][n] = __builtin_amdgcn_mfma_f32_16x16x32_bf16(af[m], bf_[n], acc[m][n], 0, 0, 0);
      }
    }
#pragma unroll
    for (int m = 0; m < 4; ++m)
#pragma unroll
      for (int n = 0; n < 4; ++n)
#pragma unroll
        for (int q = 0; q < 4; ++q) {
          int tr = wm + m * 16 + lhi * 4 + q;
          int scol = nt2 * 128 + wn + n * 16 + l15;
          int tg = q0 + tr;
          float val = acc[m][n][q];
          if (scol < tg)
            val *= sgw[scol] * expf(sc[tg - 1] - sc[scol]);
          else
            val = 0.f;
          int byte = (scol * 2) ^ ((tr & 7) << 4);
          Ps[tr * 256 + (byte >> 1)] = (bf16_t)val;
        }
  }
  __syncthreads();
  // ---- PV phase ----
  {
    const bf16_t* Bb = vt + (size_t)b * Mc * Tc;
    f32x4 acc[4][4] = {};
#pragma unroll
    for (int ks = 0; ks < 4; ++ks) {
#pragma unroll
      for (int h = 0; h < 2; ++h) {
        bf16x8 af[4], bf_[4];
#pragma unroll
        for (int m = 0; m < 4; ++m) {
          int row = wm + m * 16 + l15;
          int byteA = (ks * 128 + h * 64 + lhi * 16) ^ ((row & 7) << 4);
          af[m] = *(const bf16x8*)(Ps + row * 256 + (byteA >> 1));
        }
        int ko = ks * 64 + h * 32 + lhi * 8;
#pragma unroll
        for (int n = 0; n < 4; ++n)
          bf_[n] = *(const bf16x8*)(Bb + (size_t)(wn + n * 16 + l15) * Tc + ko);
#pragma unroll
        for (int m = 0; m < 4; ++m)
#pragma unroll
          for (int n = 0; n < 4; ++n)
            acc[m][n] = __builtin_amdgcn_mfma_f32_16x16x32_bf16(af[m], bf_[n], acc[m][n], 0, 0, 0);
      }
    }
#pragma unroll
    for (int m = 0; m < 4; ++m)
#pragma unroll
      for (int n = 0; n < 4; ++n)
#pragma unroll
        for (int q = 0; q < 4; ++q) {
          int row = wm + m * 16 + lhi * 4 + q;
          int col = wn + n * 16 + l15;
          rd[(size_t)(b * Tc + q0 + row) * Mc + col] = (bf16_t)acc[m][n][q];
        }
  }
}

// ---------------------------------------------------------------- launcher
extern "C" void kernel_launch(void* const* d_in, const int* in_sizes, int n_in,
                              void* d_out, int out_size, void* d_ws, size_t ws_size,
                              hipStream_t stream) {
  const int* idx = (const int*)d_in[0];
  const float* center = (const float*)d_in[1];
  // d_in[2] offset: dead code (x = (b_min+b_max)/2 = center)
  const float* wk = (const float*)d_in[3];
  const float* bk = (const float*)d_in[4];
  const float* wq = (const float*)d_in[5];
  const float* bq = (const float*)d_in[6];
  const float* wv = (const float*)d_in[7];
  const float* bv = (const float*)d_in[8];
  const float* wo = (const float*)d_in[9];
  const float* bo = (const float*)d_in[10];
  const float* wgw = (const float*)d_in[11];
  const float* bgw = (const float*)d_in[12];
  const float* wgf = (const float*)d_in[13];
  const float* bgf = (const float*)d_in[14];
  const float* ln1_g = (const float*)d_in[15];
  const float* ln1_b = (const float*)d_in[16];
  const float* ln2_g = (const float*)d_in[17];
  const float* ln2_b = (const float*)d_in[18];
  const float* w1 = (const float*)d_in[19];
  const float* b1 = (const float*)d_in[20];
  const float* w2 = (const float*)d_in[21];
  const float* b2 = (const float*)d_in[22];
  const float* lnf_g = (const float*)d_in[23];
  const float* lnf_b = (const float*)d_in[24];
  const float* logit_scale = (const float*)d_in[25];

  float* logits = (float*)d_out;                     // [R, V] fp32
  float* states = logits + (size_t)Rc * Vc;          // [L, B, M, M] fp32

  char* p = (char*)d_ws;
  auto alloc = [&](size_t bytes) -> char* {
    char* r = p;
    p += (bytes + 255) & ~(size_t)255;
    return r;
  };
  float* x    = (float*)alloc((size_t)Rc * Dc * 4);
  float* gwb  = (float*)alloc(Rc * 4);
  float* gfb  = (float*)alloc(Rc * 4);
  float* bkqv = (float*)alloc(Lc * 512 * 4);
  float* part = (float*)alloc((size_t)2 * Rc * Dc * 4);   // split-K partials for w2
  bf16_t* xn_bf   = (bf16_t*)alloc((size_t)Rc * Dc * 2);
  bf16_t* h1_bf   = (bf16_t*)alloc((size_t)Rc * Hc * 2);
  bf16_t* k_bf    = (bf16_t*)alloc((size_t)Rc * Mc * 2);
  bf16_t* q_bf    = (bf16_t*)alloc((size_t)Rc * Mc * 2);
  bf16_t* rd_bf   = (bf16_t*)alloc((size_t)Rc * Mc * 2);
  bf16_t* kt_bf   = (bf16_t*)alloc((size_t)Bc * Mc * Tc * 2);
  bf16_t* vt_bf   = (bf16_t*)alloc((size_t)Bc * Mc * Tc * 2);
  bf16_t* cen_bf  = (bf16_t*)alloc((size_t)Vc * Dc * 2);
  bf16_t* w1_bf   = (bf16_t*)alloc((size_t)Lc * Hc * Dc * 2);
  bf16_t* w2_bf   = (bf16_t*)alloc((size_t)Lc * Dc * Hc * 2);
  bf16_t* wo_bf   = (bf16_t*)alloc((size_t)Lc * Dc * Mc * 2);
  bf16_t* wkqv_bf = (bf16_t*)alloc((size_t)Lc * 512 * Dc * 2);

  // merged preamble: cvt + packs + gather/ln1
  pre_k<<<13768, 256, 0, stream>>>(center, cen_bf, w1, w1_bf, w2, w2_bf, wo, wo_bf,
                                   wk, wq, wv, wgw, wgf, wkqv_bf,
                                   bk, bq, bv, bgw, bgf, bkqv,
                                   idx, ln1_g, ln1_b, x, xn_bf);

  const long long zero = 0;
  for (int l = 0; l < Lc; ++l) {
    // kqv GEMM + fused l2norm/transpose/gates epilogue
    kqvprep_k<<<dim3(4, 16), 256, 0, stream>>>(
        xn_bf, wkqv_bf + (size_t)l * 512 * Dc, bkqv + l * 512,
        k_bf, q_bf, kt_bf, vt_bf, gwb, gfb);

    // fused P(decay) + PV + states (in-kernel scan, in-register wgt)
    attn_k<<<dim3(3, Bc), 256, 0, stream>>>(q_bf, k_bf, vt_bf, kt_bf, gwb, gfb,
                                            rd_bf, states + (size_t)l * Bc * Mc * Mc);

    // x += reads @ wo^T + bo
    mms_k<A_NONE, true, false><<<dim3(4, 16, 1), 256, 0, stream>>>(
        rd_bf, wo_bf + (size_t)l * Dc * Mc, x, bo + (size_t)l * Dc,
        Mc, Mc, Mc, Dc, zero, zero, zero);

    ln_k<<<Rc, 64, 0, stream>>>(x, ln2_g + (size_t)l * Dc, ln2_b + (size_t)l * Dc, xn_bf);

    // h1 = gelu(xn @ w1^T + b1) -> bf16
    mms_k<A_GELU, false, true><<<dim3(16, 16, 1), 256, 0, stream>>>(
        xn_bf, w1_bf + (size_t)l * Hc * Dc, h1_bf, b1 + (size_t)l * Hc,
        Dc, Dc, Dc, Hc, zero, zero, zero);

    // w2 split-K=2: partials
    mms_k<A_NONE, false, false><<<dim3(4, 16, 2), 256, 0, stream>>>(
        h1_bf, w2_bf + (size_t)l * Dc * Hc, part, nullptr,
        Hc / 2, Hc, Hc, Dc, (long long)(Hc / 2), (long long)(Hc / 2), (long long)Rc * Dc);

    // x += partials + b2 ; xn = LN(x) with next layer's ln1 (or lnf after last layer)
    const float* ng = (l < Lc - 1) ? ln1_g + (size_t)(l + 1) * Dc : lnf_g;
    const float* nb = (l < Lc - 1) ? ln1_b + (size_t)(l + 1) * Dc : lnf_b;
    redln_k<<<Rc, 64, 0, stream>>>(part, b2 + (size_t)l * Dc, x, ng, nb, xn_bf);
  }

  // logits = (xn @ center^T) * logit_scale/sqrt(512)   (XCD-swizzled, 4000 blocks)
  mm_k<A_NONE, false, true, false, true><<<dim3(250, 16, 1), 256, 0, stream>>>(
      xn_bf, cen_bf, logits, nullptr, Dc, Dc, Dc, Vc, zero, zero, zero,
      logit_scale, 0.044194173824159223f);
}